// Round 7
// baseline (246.291 us; speedup 1.0000x reference)
//
#include <hip/hip_runtime.h>
#include <stdint.h>

// BeeAlgorithm collapses to: best = scout[argmin_s ||scout_positions[s] + 0.1*normal(k_scout)[s,:]||]
// broadcast to (8, 8192). Verified bit-exact previously (absmax 0.0).
// R9: two failure modes now MEASURED:
//   full-unroll (228us): compiler picks 64 VGPR for occupancy -> spills 133B/thr
//     -> scratch cuts occupancy to 36% + spill-op bloat; norms ~49us.
//   rolled (237us): no spills, but load->use within one iteration -> per-iter
//     s_waitcnt vmcnt(0) stall on ~900cy cold-HBM latency; norms ~58us.
// Fix: rolled outer loop (4 iters x 8 elements) + SOFTWARE PREFETCH of the next
// two float4s before computing the current two. Load-to-use distance ~1600cy of
// VALU work > 900cy HBM latency; live state ~55 VGPR -> no spill at the 64-VGPR
// allocation the compiler favors. No launch_bounds (hard pins regressed R4/R7).
// Selection math identical to R8 (passed absmax 0.0); exact output path untouched.

#define NSCOUT 2048
#define NDIM   8192
#define NBATCH 8

__host__ __device__ __forceinline__ uint32_t rotl32(uint32_t x, uint32_t r) {
  return __builtin_rotateleft32(x, r);   // -> llvm.fshl -> v_alignbit_b32
}

// Threefry-2x32, 20 rounds, exactly as jax/_src/prng.py threefry2x32 lowering.
__host__ __device__ __forceinline__ void threefry2x32(
    uint32_t k0, uint32_t k1, uint32_t x0, uint32_t x1,
    uint32_t* o0, uint32_t* o1) {
  uint32_t ks2 = k0 ^ k1 ^ 0x1BD11BDAu;
  x0 += k0; x1 += k1;
  x0 += x1; x1 = rotl32(x1, 13); x1 ^= x0;
  x0 += x1; x1 = rotl32(x1, 15); x1 ^= x0;
  x0 += x1; x1 = rotl32(x1, 26); x1 ^= x0;
  x0 += x1; x1 = rotl32(x1,  6); x1 ^= x0;
  x0 += k1; x1 += ks2 + 1u;
  x0 += x1; x1 = rotl32(x1, 17); x1 ^= x0;
  x0 += x1; x1 = rotl32(x1, 29); x1 ^= x0;
  x0 += x1; x1 = rotl32(x1, 16); x1 ^= x0;
  x0 += x1; x1 = rotl32(x1, 24); x1 ^= x0;
  x0 += ks2; x1 += k0 + 2u;
  x0 += x1; x1 = rotl32(x1, 13); x1 ^= x0;
  x0 += x1; x1 = rotl32(x1, 15); x1 ^= x0;
  x0 += x1; x1 = rotl32(x1, 26); x1 ^= x0;
  x0 += x1; x1 = rotl32(x1,  6); x1 ^= x0;
  x0 += k0; x1 += k1 + 3u;
  x0 += x1; x1 = rotl32(x1, 17); x1 ^= x0;
  x0 += x1; x1 = rotl32(x1, 29); x1 ^= x0;
  x0 += x1; x1 = rotl32(x1, 16); x1 ^= x0;
  x0 += x1; x1 = rotl32(x1, 24); x1 ^= x0;
  x0 += k1; x1 += ks2 + 4u;
  x0 += x1; x1 = rotl32(x1, 13); x1 ^= x0;
  x0 += x1; x1 = rotl32(x1, 15); x1 ^= x0;
  x0 += x1; x1 = rotl32(x1, 26); x1 ^= x0;
  x0 += x1; x1 = rotl32(x1,  6); x1 ^= x0;
  x0 += ks2; x1 += k0 + 5u;
  *o0 = x0; *o1 = x1;
}

// EXACT XLA ErfInv32 + JAX uniform->normal (bit-matched, absmax 0.0).
// Used only for the final output row (8192 elements).
__device__ __forceinline__ float jax_normal_from_bits_exact(uint32_t bits) {
  float f = __uint_as_float((bits >> 9) | 0x3f800000u) - 1.0f;
  float x = fmaxf(-0.99999994f, f * 2.0f - 0.99999994f);
  float w = -log1pf(-x * x);
  float p;
  if (w < 5.0f) {
    w = w - 2.5f;
    p = 2.81022636e-08f;
    p = 3.43273939e-07f  + p * w;
    p = -3.5233877e-06f  + p * w;
    p = -4.39150654e-06f + p * w;
    p = 0.00021858087f   + p * w;
    p = -0.00125372503f  + p * w;
    p = -0.00417768164f  + p * w;
    p = 0.246640727f     + p * w;
    p = 1.50140941f      + p * w;
  } else {
    w = sqrtf(w) - 3.0f;
    p = -0.000200214257f;
    p = 0.000100950558f  + p * w;
    p = 0.00134934322f   + p * w;
    p = 0.00434990931f   + p * w;
    p = -0.00367342844f  + p * w;
    p = 0.00573950773f   + p * w;
    p = -0.0076224613f   + p * w;
    p = 0.00943887047f   + p * w;
    p = 1.00167406f      + p * w;
    p = 2.83297682f      + p * w;
  }
  return 1.41421356f * (p * x);
}

// FAST path for the norms pass (verified absmax 0.0 in R8): central branch in
// log2 domain (coeffs b_i = a_i*(-ln2)^i with a_i the sqrt(2)*0.1-folded Giles
// coefficients). Relative error vs exact ~1e-6 — argmin margin ~3e-3 relative.
// fmax clamp kept: bits<512 would give x=-1 -> log(0) -> inf norm2.
__device__ __forceinline__ float fast_perturbed(uint32_t bits, float pos) {
  float u = __uint_as_float((bits >> 9) | 0x3f800000u);      // [1,2)
  float x = fmaxf(-0.99999994f, fmaf(u, 2.0f, -3.0f));       // ~2u-1 in (-1,1)
  float wp = __log2f(fmaf(-x, x, 1.0f));                     // log2(1-x^2) <= 0
  float p;
  if (wp > -7.2134752f) {            // w = -ln2*wp < 5  (central branch)
    float t = wp + 3.6067376f;       // t' = wp + 2.5/ln2
    p = 2.11767e-10f;
    p = fmaf(p, t, -3.73192e-09f);
    p = fmaf(p, t, -5.52623e-08f);
    p = fmaf(p, t, 9.93694e-08f);
    p = fmaf(p, t, 7.13561e-06f);
    p = fmaf(p, t, 5.90464e-05f);
    p = fmaf(p, t, -2.83878e-04f);
    p = fmaf(p, t, -2.41772e-02f);
    p = fmaf(p, t, 2.12332e-01f);
  } else {                           // rare tail (~0.33% of elements)
    float w = -0.69314718f * wp;
    float s = __builtin_amdgcn_sqrtf(w) - 3.0f;
    p = -2.83147e-05f;
    p = fmaf(p, s, 1.42766e-05f);
    p = fmaf(p, s, 1.90826e-04f);
    p = fmaf(p, s, 6.15171e-04f);
    p = fmaf(p, s, -5.19503e-04f);
    p = fmaf(p, s, 8.11691e-04f);
    p = fmaf(p, s, -1.07799e-03f);
    p = fmaf(p, s, 1.33486e-03f);
    p = fmaf(p, s, 1.41658e-01f);
    p = fmaf(p, s, 4.00645e-01f);
  }
  return fmaf(x, p, pos);   // pos + 0.1 * normal
}

// One block per scout row: approx norm^2 of perturbed row. Each block stores its
// packed (float_bits << 32 | row) key to its OWN slot — no atomics, no init.
// Norms positive -> float bits order-preserving; low-word row index gives
// first-occurrence tie-break under min, matching JAX argmin semantics.
//
// Structure (R9): rolled outer loop, 2 float4 (8 elements) per iteration, with
// next-iteration float4s PREFETCHED before the current pair is consumed. The
// vmcnt wait before consuming a0/a1 covers loads issued ~1600 VALU-cycles ago
// (8 x ~96-op chains), fully hiding ~900cy cold-HBM latency even at modest
// occupancy. Live state: 4 float4 (16) + 8 threefry pairs (16) + temps ~55 VGPR
// -> fits the compiler's preferred 64-VGPR allocation with NO spill.
__global__ void norms_kernel(
    const float* __restrict__ pos, unsigned long long* __restrict__ slots,
    uint32_t k0, uint32_t k1) {
  const int s = blockIdx.x;
  const int t = threadIdx.x;
  const float4* p4 = (const float4*)(pos + (size_t)s * NDIM) + t;
  const uint32_t jbase = (uint32_t)(s * NDIM) + (uint32_t)(t * 4);
  float acc = 0.0f;

  float4 a0 = p4[0];
  float4 a1 = p4[256];
#pragma unroll 1
  for (int k = 0; k < 4; ++k) {
    float4 n0 = a0, n1 = a1;
    if (k != 3) {                       // uniform branch (k is scalar)
      n0 = p4[(2 * k + 2) * 256];
      n1 = p4[(2 * k + 3) * 256];
    }
    const uint32_t jb0 = jbase + (uint32_t)(2 * k) * 1024u;
    const float* f0 = &a0.x;
#pragma unroll
    for (int e = 0; e < 4; ++e) {
      uint32_t b0, b1;
      threefry2x32(k0, k1, 0u, jb0 + (uint32_t)e, &b0, &b1);
      float v = fast_perturbed(b0 ^ b1, f0[e]);
      acc = fmaf(v, v, acc);
    }
    const uint32_t jb1 = jb0 + 1024u;
    const float* f1 = &a1.x;
#pragma unroll
    for (int e = 0; e < 4; ++e) {
      uint32_t b0, b1;
      threefry2x32(k0, k1, 0u, jb1 + (uint32_t)e, &b0, &b1);
      float v = fast_perturbed(b0 ^ b1, f1[e]);
      acc = fmaf(v, v, acc);
    }
    a0 = n0;
    a1 = n1;
  }
#pragma unroll
  for (int off = 32; off > 0; off >>= 1) acc += __shfl_down(acc, off, 64);
  __shared__ float wsum[4];
  if ((t & 63) == 0) wsum[t >> 6] = acc;
  __syncthreads();
  if (t == 0) {
    float norm2 = wsum[0] + wsum[1] + wsum[2] + wsum[3];
    slots[s] =
        ((unsigned long long)__float_as_uint(norm2) << 32) | (unsigned long long)s;
  }
}

// 32 blocks x 256 threads: each block min-reduces the 2048 slot keys (16 KB,
// L2-hot), then recomputes the winning row EXACTLY and writes 8 broadcast copies.
__global__ void __launch_bounds__(256) write_kernel(
    const float* __restrict__ pos, const unsigned long long* __restrict__ slots,
    float* __restrict__ out, uint32_t k0, uint32_t k1) {
  const int t = threadIdx.x;

  unsigned long long k = 0xFFFFFFFFFFFFFFFFull;
#pragma unroll
  for (int i = 0; i < NSCOUT / 256; ++i) {
    unsigned long long v = slots[i * 256 + t];
    k = (v < k) ? v : k;
  }
#pragma unroll
  for (int off = 32; off > 0; off >>= 1) {
    unsigned long long o = __shfl_down(k, off, 64);
    k = (o < k) ? o : k;
  }
  __shared__ unsigned long long wmin[4];
  if ((t & 63) == 0) wmin[t >> 6] = k;
  __syncthreads();
  unsigned long long m01 = (wmin[0] < wmin[1]) ? wmin[0] : wmin[1];
  unsigned long long m23 = (wmin[2] < wmin[3]) ? wmin[2] : wmin[3];
  unsigned long long mk  = (m01 < m23) ? m01 : m23;
  const int s = (int)(uint32_t)(mk & 0xFFFFFFFFull);

  const int d = blockIdx.x * 256 + t;
  uint32_t j = (uint32_t)(s * NDIM + d);
  uint32_t b0, b1;
  threefry2x32(k0, k1, 0u, j, &b0, &b1);
  float n = jax_normal_from_bits_exact(b0 ^ b1);
  float v = pos[(size_t)s * NDIM + d] + n * 0.1f;
#pragma unroll
  for (int r = 0; r < NBATCH; ++r) out[r * NDIM + d] = v;
}

extern "C" void kernel_launch(void* const* d_in, const int* in_sizes, int n_in,
                              void* d_out, int out_size, void* d_ws, size_t ws_size,
                              hipStream_t stream) {
  (void)in_sizes; (void)n_in; (void)out_size; (void)ws_size;
  const float* scout_pos = (const float*)d_in[1];  // scout_positions [2048, 8192] f32
  float* out = (float*)d_out;                      // [8, 8192] f32
  unsigned long long* slots = (unsigned long long*)d_ws;  // 2048 * 8 B = 16 KB

  // k_scout = split(key(42), 4)[0] under partitionable threefry.
  uint32_t k0, k1;
  threefry2x32(0u, 42u, 0u, 0u, &k0, &k1);

  hipLaunchKernelGGL(norms_kernel, dim3(NSCOUT), dim3(256), 0, stream,
                     scout_pos, slots, k0, k1);
  hipLaunchKernelGGL(write_kernel, dim3(NDIM / 256), dim3(256), 0, stream,
                     scout_pos, slots, out, k0, k1);
}

// Round 8
// 227.412 us; speedup vs baseline: 1.0830x; 1.0830x over previous
//
#include <hip/hip_runtime.h>
#include <stdint.h>

// BeeAlgorithm collapses to: best = scout[argmin_s ||scout_positions[s] + 0.1*normal(k_scout)[s,:]||]
// broadcast to (8, 8192). Verified bit-exact previously (absmax 0.0).
// R10: schedule-level fixes of the 32-elem/thread decomposition all LOST to the
// spilling full-unroll (R5 228 < rolled 237 < prefetch 246). New axis: shrink
// per-thread work so full-unroll is spill-free BY CONSTRUCTION. 4 blocks per row
// (8192 blocks x 256 thr, 8 elem/thread): straight-line ~790-instr body, 2 float4
// hoisted + 8 threefry chains ~= 40 live VGPR -> no spill, no loop stalls, and
// the compiler keeps its preferred greedy schedule. Each block writes a partial
// norm^2 (no atomics, no init); write_kernel sums 4 partials/row (one float4,
// deterministic order; selection margin ~3e-3 rel, approx err ~1e-6) then does
// the same packed-key min-reduce. Exact XLA output path untouched.

#define NSCOUT 2048
#define NDIM   8192
#define NBATCH 8

__host__ __device__ __forceinline__ uint32_t rotl32(uint32_t x, uint32_t r) {
  return __builtin_rotateleft32(x, r);   // -> llvm.fshl -> v_alignbit_b32
}

// Threefry-2x32, 20 rounds, exactly as jax/_src/prng.py threefry2x32 lowering.
__host__ __device__ __forceinline__ void threefry2x32(
    uint32_t k0, uint32_t k1, uint32_t x0, uint32_t x1,
    uint32_t* o0, uint32_t* o1) {
  uint32_t ks2 = k0 ^ k1 ^ 0x1BD11BDAu;
  x0 += k0; x1 += k1;
  x0 += x1; x1 = rotl32(x1, 13); x1 ^= x0;
  x0 += x1; x1 = rotl32(x1, 15); x1 ^= x0;
  x0 += x1; x1 = rotl32(x1, 26); x1 ^= x0;
  x0 += x1; x1 = rotl32(x1,  6); x1 ^= x0;
  x0 += k1; x1 += ks2 + 1u;
  x0 += x1; x1 = rotl32(x1, 17); x1 ^= x0;
  x0 += x1; x1 = rotl32(x1, 29); x1 ^= x0;
  x0 += x1; x1 = rotl32(x1, 16); x1 ^= x0;
  x0 += x1; x1 = rotl32(x1, 24); x1 ^= x0;
  x0 += ks2; x1 += k0 + 2u;
  x0 += x1; x1 = rotl32(x1, 13); x1 ^= x0;
  x0 += x1; x1 = rotl32(x1, 15); x1 ^= x0;
  x0 += x1; x1 = rotl32(x1, 26); x1 ^= x0;
  x0 += x1; x1 = rotl32(x1,  6); x1 ^= x0;
  x0 += k0; x1 += k1 + 3u;
  x0 += x1; x1 = rotl32(x1, 17); x1 ^= x0;
  x0 += x1; x1 = rotl32(x1, 29); x1 ^= x0;
  x0 += x1; x1 = rotl32(x1, 16); x1 ^= x0;
  x0 += x1; x1 = rotl32(x1, 24); x1 ^= x0;
  x0 += k1; x1 += ks2 + 4u;
  x0 += x1; x1 = rotl32(x1, 13); x1 ^= x0;
  x0 += x1; x1 = rotl32(x1, 15); x1 ^= x0;
  x0 += x1; x1 = rotl32(x1, 26); x1 ^= x0;
  x0 += x1; x1 = rotl32(x1,  6); x1 ^= x0;
  x0 += ks2; x1 += k0 + 5u;
  *o0 = x0; *o1 = x1;
}

// EXACT XLA ErfInv32 + JAX uniform->normal (bit-matched, absmax 0.0).
// Used only for the final output row (8192 elements).
__device__ __forceinline__ float jax_normal_from_bits_exact(uint32_t bits) {
  float f = __uint_as_float((bits >> 9) | 0x3f800000u) - 1.0f;
  float x = fmaxf(-0.99999994f, f * 2.0f - 0.99999994f);
  float w = -log1pf(-x * x);
  float p;
  if (w < 5.0f) {
    w = w - 2.5f;
    p = 2.81022636e-08f;
    p = 3.43273939e-07f  + p * w;
    p = -3.5233877e-06f  + p * w;
    p = -4.39150654e-06f + p * w;
    p = 0.00021858087f   + p * w;
    p = -0.00125372503f  + p * w;
    p = -0.00417768164f  + p * w;
    p = 0.246640727f     + p * w;
    p = 1.50140941f      + p * w;
  } else {
    w = sqrtf(w) - 3.0f;
    p = -0.000200214257f;
    p = 0.000100950558f  + p * w;
    p = 0.00134934322f   + p * w;
    p = 0.00434990931f   + p * w;
    p = -0.00367342844f  + p * w;
    p = 0.00573950773f   + p * w;
    p = -0.0076224613f   + p * w;
    p = 0.00943887047f   + p * w;
    p = 1.00167406f      + p * w;
    p = 2.83297682f      + p * w;
  }
  return 1.41421356f * (p * x);
}

// FAST path for the norms pass (verified absmax 0.0 in R8/R9): central branch in
// log2 domain (coeffs b_i = a_i*(-ln2)^i with a_i the sqrt(2)*0.1-folded Giles
// coefficients). Relative error vs exact ~1e-6 — argmin margin ~3e-3 relative.
// fmax clamp kept: bits<512 would give x=-1 -> log(0) -> inf norm2.
__device__ __forceinline__ float fast_perturbed(uint32_t bits, float pos) {
  float u = __uint_as_float((bits >> 9) | 0x3f800000u);      // [1,2)
  float x = fmaxf(-0.99999994f, fmaf(u, 2.0f, -3.0f));       // ~2u-1 in (-1,1)
  float wp = __log2f(fmaf(-x, x, 1.0f));                     // log2(1-x^2) <= 0
  float p;
  if (wp > -7.2134752f) {            // w = -ln2*wp < 5  (central branch)
    float t = wp + 3.6067376f;       // t' = wp + 2.5/ln2
    p = 2.11767e-10f;
    p = fmaf(p, t, -3.73192e-09f);
    p = fmaf(p, t, -5.52623e-08f);
    p = fmaf(p, t, 9.93694e-08f);
    p = fmaf(p, t, 7.13561e-06f);
    p = fmaf(p, t, 5.90464e-05f);
    p = fmaf(p, t, -2.83878e-04f);
    p = fmaf(p, t, -2.41772e-02f);
    p = fmaf(p, t, 2.12332e-01f);
  } else {                           // rare tail (~0.33% of elements)
    float w = -0.69314718f * wp;
    float s = __builtin_amdgcn_sqrtf(w) - 3.0f;
    p = -2.83147e-05f;
    p = fmaf(p, s, 1.42766e-05f);
    p = fmaf(p, s, 1.90826e-04f);
    p = fmaf(p, s, 6.15171e-04f);
    p = fmaf(p, s, -5.19503e-04f);
    p = fmaf(p, s, 8.11691e-04f);
    p = fmaf(p, s, -1.07799e-03f);
    p = fmaf(p, s, 1.33486e-03f);
    p = fmaf(p, s, 1.41658e-01f);
    p = fmaf(p, s, 4.00645e-01f);
  }
  return fmaf(x, p, pos);   // pos + 0.1 * normal
}

// 4 blocks per row (blockIdx = s*4 + q): each block computes the partial norm^2
// of 2048 elements (8 per thread, fully unrolled straight-line body) and stores
// it to partials[blockIdx]. Live state ~40 VGPR -> no spill at any allocation;
// no loop -> no per-iteration waitcnt stalls. No atomics, no init (every slot
// written unconditionally).
__global__ void norms_kernel(
    const float* __restrict__ pos, float* __restrict__ partials,
    uint32_t k0, uint32_t k1) {
  const int b = blockIdx.x;
  const int s = b >> 2;          // row
  const int q = b & 3;           // quarter within row
  const int t = threadIdx.x;
  // float4 indices within the row: f0 = q*512 + t, f1 = f0 + 256.
  const int f0 = q * 512 + t;
  const float4* p4 = (const float4*)(pos + (size_t)s * NDIM);
  float4 a0 = p4[f0];
  float4 a1 = p4[f0 + 256];
  const uint32_t jb0 = (uint32_t)(s * NDIM) + (uint32_t)(f0 * 4);
  const uint32_t jb1 = jb0 + 1024u;

  float acc = 0.0f;
  const float* f0p = &a0.x;
#pragma unroll
  for (int e = 0; e < 4; ++e) {
    uint32_t b0, b1;
    threefry2x32(k0, k1, 0u, jb0 + (uint32_t)e, &b0, &b1);
    float v = fast_perturbed(b0 ^ b1, f0p[e]);
    acc = fmaf(v, v, acc);
  }
  const float* f1p = &a1.x;
#pragma unroll
  for (int e = 0; e < 4; ++e) {
    uint32_t b0, b1;
    threefry2x32(k0, k1, 0u, jb1 + (uint32_t)e, &b0, &b1);
    float v = fast_perturbed(b0 ^ b1, f1p[e]);
    acc = fmaf(v, v, acc);
  }

#pragma unroll
  for (int off = 32; off > 0; off >>= 1) acc += __shfl_down(acc, off, 64);
  __shared__ float wsum[4];
  if ((t & 63) == 0) wsum[t >> 6] = acc;
  __syncthreads();
  if (t == 0) partials[b] = wsum[0] + wsum[1] + wsum[2] + wsum[3];
}

// 32 blocks x 256 threads: each block redundantly reduces the 2048 rows (each
// row = one float4 of partials, summed in fixed order -> deterministic key),
// finds the packed-key min (norm2 bits << 32 | row; first-occurrence tie-break
// = JAX argmin semantics), then recomputes the winning row EXACTLY and writes
// the 8 broadcast copies.
__global__ void __launch_bounds__(256) write_kernel(
    const float* __restrict__ pos, const float* __restrict__ partials,
    float* __restrict__ out, uint32_t k0, uint32_t k1) {
  const int t = threadIdx.x;
  const float4* pp = (const float4*)partials;

  unsigned long long k = 0xFFFFFFFFFFFFFFFFull;
#pragma unroll
  for (int i = 0; i < NSCOUT / 256; ++i) {
    const int row = i * 256 + t;
    float4 p = pp[row];
    float norm2 = ((p.x + p.y) + (p.z + p.w));
    unsigned long long v =
        ((unsigned long long)__float_as_uint(norm2) << 32) | (unsigned long long)row;
    k = (v < k) ? v : k;
  }
#pragma unroll
  for (int off = 32; off > 0; off >>= 1) {
    unsigned long long o = __shfl_down(k, off, 64);
    k = (o < k) ? o : k;
  }
  __shared__ unsigned long long wmin[4];
  if ((t & 63) == 0) wmin[t >> 6] = k;
  __syncthreads();
  unsigned long long m01 = (wmin[0] < wmin[1]) ? wmin[0] : wmin[1];
  unsigned long long m23 = (wmin[2] < wmin[3]) ? wmin[2] : wmin[3];
  unsigned long long mk  = (m01 < m23) ? m01 : m23;
  const int s = (int)(uint32_t)(mk & 0xFFFFFFFFull);

  const int d = blockIdx.x * 256 + t;
  uint32_t j = (uint32_t)(s * NDIM + d);
  uint32_t b0, b1;
  threefry2x32(k0, k1, 0u, j, &b0, &b1);
  float n = jax_normal_from_bits_exact(b0 ^ b1);
  float v = pos[(size_t)s * NDIM + d] + n * 0.1f;
#pragma unroll
  for (int r = 0; r < NBATCH; ++r) out[r * NDIM + d] = v;
}

extern "C" void kernel_launch(void* const* d_in, const int* in_sizes, int n_in,
                              void* d_out, int out_size, void* d_ws, size_t ws_size,
                              hipStream_t stream) {
  (void)in_sizes; (void)n_in; (void)out_size; (void)ws_size;
  const float* scout_pos = (const float*)d_in[1];  // scout_positions [2048, 8192] f32
  float* out = (float*)d_out;                      // [8, 8192] f32
  float* partials = (float*)d_ws;                  // 2048*4 f32 = 32 KB

  // k_scout = split(key(42), 4)[0] under partitionable threefry.
  uint32_t k0, k1;
  threefry2x32(0u, 42u, 0u, 0u, &k0, &k1);

  hipLaunchKernelGGL(norms_kernel, dim3(NSCOUT * 4), dim3(256), 0, stream,
                     scout_pos, partials, k0, k1);
  hipLaunchKernelGGL(write_kernel, dim3(NDIM / 256), dim3(256), 0, stream,
                     scout_pos, partials, out, k0, k1);
}